// Round 17
// baseline (262.858 us; speedup 1.0000x reference)
//
#include <hip/hip_runtime.h>
#include <hip/hip_bf16.h>

typedef __hip_bfloat16 bf16;
typedef __attribute__((ext_vector_type(8))) short s8v;   // 8 bf16 (4 VGPRs)
typedef __attribute__((ext_vector_type(4))) float f4v;   // 4 fp32 acc

#define NN 32768   // total nodes
#define EE 262144  // edges
#define GG 512     // graphs
#define LDW 520    // conv12 tile stride (bf16): 520*2B -> 2-way bank alias (free)
#define ECAP 256   // LDS edge-weight capacity per conv12f block (mean 128, +11 sigma)

__device__ __forceinline__ float2 unpk(unsigned u) {
  float2 r;
  r.x = __uint_as_float(u << 16);
  r.y = __uint_as_float(u & 0xffff0000u);
  return r;
}
__device__ __forceinline__ unsigned pk(float x, float y) {
  union { bf16 h[2]; unsigned u; } p;
  p.h[0] = __float2bfloat16(x);
  p.h[1] = __float2bfloat16(y);
  return p.u;
}
__device__ __forceinline__ short f2bf_bits(float x) {
  bf16 h = __float2bfloat16(x);
  return *reinterpret_cast<short*>(&h);
}
__device__ __forceinline__ float wred_sum(float v) {
#pragma unroll
  for (int o = 32; o; o >>= 1) v += __shfl_xor(v, o, 64);
  return v;
}

// pack one weight matrix into MFMA B-fragment order
__device__ __forceinline__ void packB_one(const float* W, int N, int K, int id, s8v* Bp) {
  int lane = id & 63;
  int tmp = id >> 6;
  int ksteps = K >> 5;
  int ks = tmp % ksteps;
  int nt = tmp / ksteps;
  int n = nt * 16 + (lane & 15);
  int kbase = ks * 32 + (lane >> 4) * 8;
  s8v r;
#pragma unroll
  for (int j = 0; j < 8; j++) r[j] = f2bf_bits(W[(size_t)(kbase + j) * N + n]);
  Bp[id] = r;
}

// ================= K1: hist + pack(Bp1,Bp2) + fold1 + emb2 + start-weight folds ======
__global__ __launch_bounds__(256) void prep_kernel(
    const int* __restrict__ dst, int* __restrict__ indeg,
    const float* __restrict__ W1, s8v* __restrict__ Bp1,
    const float* __restrict__ W2, s8v* __restrict__ Bp2,
    const float* __restrict__ a_src1, const float* __restrict__ a_dst1,
    float* __restrict__ ws1, float* __restrict__ wd1,
    const float* __restrict__ emb, const float* __restrict__ Wnode,
    const float* __restrict__ bnode, bf16* __restrict__ emb2_b,
    const float* __restrict__ Wv, const float* __restrict__ Wt,
    const float* __restrict__ Ws,
    const float* __restrict__ bv, const float* __restrict__ bt,
    const float* __restrict__ bstart,
    float* __restrict__ Wvs, float* __restrict__ Wts,
    float* __restrict__ bs2) {
  int b = blockIdx.x, tid = threadIdx.x;
  if (b < 1024) {
    int e = b * 256 + tid;
    atomicAdd(&indeg[dst[e]], 1);
  } else if (b < 1056) {
    packB_one(W1, 512, 128, (b - 1024) * 256 + tid, Bp1);
  } else if (b < 1088) {
    packB_one(W2, 128, 512, (b - 1056) * 256 + tid, Bp2);
  } else if (b < 1090) {
    int id = (b - 1088) * 256 + tid;   // 512 outputs
    int h = id >> 7, k = id & 127;
    float s = 0.f, d = 0.f;
    for (int c = 0; c < 128; c++) {
      float w0 = W1[(size_t)k * 512 + h * 128 + c];
      s = fmaf(w0, a_src1[h * 128 + c], s);
      d = fmaf(w0, a_dst1[h * 128 + c], d);
    }
    ws1[id] = s;
    wd1[id] = d;
  } else if (b < 1192) {
    // emb2 = emb @ Wnode + bnode  (M=51,N=128,K=128), split-K over 4 slices
    __shared__ float red[256];
    int bb = b - 1090;
    int lo = tid & 63, slice = tid >> 6;
    long oid = (long)bb * 64 + lo;
    bool live = (oid < 51L * 128);
    int m = 0, n = 0;
    if (live) { m = (int)(oid >> 7); n = (int)(oid & 127); }
    float acc = 0.f;
    if (live) {
      const float* Ar = emb + (size_t)m * 128;
      for (int k = slice * 32; k < slice * 32 + 32; k++)
        acc = fmaf(Ar[k], Wnode[(size_t)k * 128 + n], acc);
    }
    red[tid] = acc;
    __syncthreads();
    if (slice == 0 && live) {
      float v = red[lo] + red[64 + lo] + red[128 + lo] + red[192 + lo];
      emb2_b[(size_t)m * 128 + n] = __float2bfloat16(v + bnode[n]);
    }
  } else if (b < 1576) {
    // folded start weights (fp32): Wvs = Wv @ Ws[0:128,:], Wts = Wt @ Ws[128:256,:]
    int id = (b - 1192) * 256 + tid;   // [0, 98304) pairs
    bool isT = id >= 49152;
    int o = isT ? id - 49152 : id;
    int k = o >> 6, cp = o & 63, c0 = cp * 2;
    const float* Wrow = (isT ? Wt : Wv) + (size_t)k * 128;
    const float* Wsc = Ws + (isT ? (size_t)128 * 128 : 0);
    float s0 = 0.f, s1 = 0.f;
    for (int j = 0; j < 128; j++) {
      float w = Wrow[j];
      float2 q = *(const float2*)(Wsc + (size_t)j * 128 + c0);
      s0 = fmaf(w, q.x, s0);
      s1 = fmaf(w, q.y, s1);
    }
    float* dp = (isT ? Wts : Wvs) + (size_t)k * 128 + c0;
    dp[0] = s0;
    dp[1] = s1;
  } else {
    // b_s = bstart + bv @ Ws[0:128,:] + bt @ Ws[128:256,:]
    if (tid < 128) {
      float s = bstart[tid];
      for (int k = 0; k < 128; k++) {
        s = fmaf(bv[k], Ws[(size_t)k * 128 + tid], s);
        s = fmaf(bt[k], Ws[(size_t)(128 + k) * 128 + tid], s);
      }
      bs2[tid] = s;
    }
  }
}

// ================= K2: block 0 = CSR scan; blocks 1..512 = start rows ================
__global__ __launch_bounds__(1024) void scan_start_kernel(
    const int* __restrict__ indeg, int* __restrict__ off, int* __restrict__ cursor,
    const float* __restrict__ tf, const float* __restrict__ vf,
    const float* __restrict__ Wvs, const float* __restrict__ Wts,
    const float* __restrict__ bs2, bf16* __restrict__ start_b) {
  int t = threadIdx.x;
  if (blockIdx.x == 0) {
    __shared__ int sh[1024];
    int loc[32];
    int s = 0;
    int base = t * 32;
#pragma unroll
    for (int j = 0; j < 32; j++) { loc[j] = indeg[base + j]; s += loc[j]; }
    sh[t] = s;
    __syncthreads();
    for (int d = 1; d < 1024; d <<= 1) {
      int v = (t >= d) ? sh[t - d] : 0;
      __syncthreads();
      sh[t] += v;
      __syncthreads();
    }
    int run = (t == 0) ? 0 : sh[t - 1];
#pragma unroll
    for (int j = 0; j < 32; j++) { off[base + j] = run; cursor[base + j] = run; run += loc[j]; }
    if (t == 1023) off[NN] = run;
    return;
  }
  __shared__ float red[1024];
  int g = blockIdx.x - 1;
  int c = t & 127, slice = t >> 7;          // 8 K-slices of 96
  const float* vrow = vf + (size_t)g * 768;
  const float* trow = tf + (size_t)g * 768;
  float acc = 0.f;
  int k0 = slice * 96;
#pragma unroll 4
  for (int k = k0; k < k0 + 96; k++)
    acc = fmaf(vrow[k], Wvs[(size_t)k * 128 + c], fmaf(trow[k], Wts[(size_t)k * 128 + c], acc));
  red[t] = acc;
  __syncthreads();
  if (t < 512) red[t] += red[t + 512];
  __syncthreads();
  if (t < 256) red[t] += red[t + 256];
  __syncthreads();
  if (t < 128) {
    float s = red[t] + red[t + 128] + bs2[t];
    start_b[(size_t)g * 128 + t] = __float2bfloat16(s);
  }
}

// ================= K3: CSR fill (blocks 0-1023, also edst) + fused LN + conv1 scores =
__global__ __launch_bounds__(256) void fill_ln_kernel(
    const int* __restrict__ src, const int* __restrict__ dst,
    int* __restrict__ cursor, int* __restrict__ esrc, int* __restrict__ edst,
    const unsigned* __restrict__ start_b, const unsigned* __restrict__ emb2_b,
    const int* __restrict__ m_idx, const float* __restrict__ lng,
    const float* __restrict__ lnb, const float* __restrict__ ws1,
    const float* __restrict__ wd1, unsigned* __restrict__ x0b,
    float* __restrict__ als, float* __restrict__ ald) {
  int b = blockIdx.x;
  if (b < 1024) {
    int e = b * 256 + threadIdx.x;
    int d = dst[e];
    int p = atomicAdd(&cursor[d], 1);
    esrc[p] = src[e];
    edst[p] = d;
    return;
  }
  int bb = b - 1024;
  int i = bb * 4 + (threadIdx.x >> 6);
  int lane = threadIdx.x & 63;
  int g = i >> 6, n = i & 63;
  const unsigned* row = (n == 0) ? (start_b + (size_t)g * 64) : (emb2_b + (size_t)m_idx[i] * 64);
  float2 v = unpk(row[lane]);
  float mu = wred_sum(v.x + v.y) * (1.f / 128.f);
  float dx = v.x - mu, dy = v.y - mu;
  float var = wred_sum(dx * dx + dy * dy) * (1.f / 128.f);
  float rstd = rsqrtf(var + 1e-6f);
  float2 gg = ((const float2*)lng)[lane];
  float2 bbv = ((const float2*)lnb)[lane];
  float xx = dx * rstd * gg.x + bbv.x;
  float xy = dy * rstd * gg.y + bbv.y;
  x0b[(size_t)i * 64 + lane] = pk(xx, xy);
#pragma unroll
  for (int h = 0; h < 4; h++) {
    float2 s2 = ((const float2*)(ws1 + h * 128))[lane];
    float2 d2 = ((const float2*)(wd1 + h * 128))[lane];
    float ps = wred_sum(xx * s2.x + xy * s2.y);
    float pd = wred_sum(xx * d2.x + xy * d2.y);
    if (lane == 0) { als[i * 4 + h] = ps; ald[i * 4 + h] = pd; }
  }
}

// ================= K5: FUSED conv1-scores(A0) + aggregate(+denom) + GEMMs + al2 =======
// Round-13 structure; ECAP 1024->256 cuts LDS 33.3->20.7 KB => 7 blocks/CU (28 waves).
__global__ __launch_bounds__(256) void conv12f_kernel(
    const uint4* __restrict__ x0,
    float4* __restrict__ awg,
    const float4* __restrict__ als4, const float4* __restrict__ ald4,
    const int* __restrict__ off, const int* __restrict__ esrc,
    const int* __restrict__ edst,
    const s8v* __restrict__ Bp1, const float* __restrict__ b1,
    const s8v* __restrict__ Bp2,
    const float* __restrict__ a_src2, const float* __restrict__ a_dst2,
    short* __restrict__ xp2, float* __restrict__ als2, float* __restrict__ ald2) {
  __shared__ short lds[16 * LDW];
  __shared__ float4 awlds[ECAP];
  int tid = threadIdx.x;
  int brow = blockIdx.x * 16;
  int e0b = off[brow], e1b = off[brow + 16];
  // ---- phase A0: edge scores, one thread per edge, into LDS (overflow -> global) ----
  for (int e = e0b + tid; e < e1b; e += 256) {
    float4 a = als4[esrc[e]];
    float4 d = ald4[edst[e]];
    float v0 = a.x + d.x, v1 = a.y + d.y, v2 = a.z + d.z, v3 = a.w + d.w;
    v0 = v0 > 0.f ? v0 : 0.2f * v0; v1 = v1 > 0.f ? v1 : 0.2f * v1;
    v2 = v2 > 0.f ? v2 : 0.2f * v2; v3 = v3 > 0.f ? v3 : 0.2f * v3;
    float4 wv = make_float4(__expf(v0), __expf(v1), __expf(v2), __expf(v3));
    int idx = e - e0b;
    if (idx < ECAP) awlds[idx] = wv;
    else awg[e] = wv;
  }
  __syncthreads();
  // ---- phase A: aggregate y1 tile (4 heads x 128 cols) into LDS, denom fused ----
  {
    int c8 = tid & 15, rsub = tid >> 4;   // rsub 0..15, one row per thread-slice
    int i = brow + rsub;
    float4 sa = als4[i], sd = ald4[i];
    float u0 = sa.x + sd.x, u1 = sa.y + sd.y, u2 = sa.z + sd.z, u3 = sa.w + sd.w;
    u0 = u0 > 0.f ? u0 : 0.2f * u0; u1 = u1 > 0.f ? u1 : 0.2f * u1;
    u2 = u2 > 0.f ? u2 : 0.2f * u2; u3 = u3 > 0.f ? u3 : 0.2f * u3;
    float sw0 = __expf(u0), sw1 = __expf(u1), sw2 = __expf(u2), sw3 = __expf(u3);
    float dn0 = sw0, dn1 = sw1, dn2 = sw2, dn3 = sw3;
    uint4 xv = x0[(size_t)i * 16 + c8];
    float x[8];
    { float2 p0 = unpk(xv.x), p1 = unpk(xv.y), p2 = unpk(xv.z), p3 = unpk(xv.w);
      x[0]=p0.x; x[1]=p0.y; x[2]=p1.x; x[3]=p1.y; x[4]=p2.x; x[5]=p2.y; x[6]=p3.x; x[7]=p3.y; }
    float acc[4][8];
#pragma unroll
    for (int j = 0; j < 8; j++) {
      acc[0][j] = sw0 * x[j]; acc[1][j] = sw1 * x[j];
      acc[2][j] = sw2 * x[j]; acc[3][j] = sw3 * x[j];
    }
    int e0 = off[i], e1 = off[i + 1];
    int e = e0;
    for (; e + 1 < e1; e += 2) {
      int sA = esrc[e], sB = esrc[e + 1];
      int iA = e - e0b, iB = iA + 1;
      float4 wA = (iA < ECAP) ? awlds[iA] : awg[e];
      float4 wB = (iB < ECAP) ? awlds[iB] : awg[e + 1];
      uint4 mA = x0[(size_t)sA * 16 + c8];
      uint4 mB = x0[(size_t)sB * 16 + c8];
      float2 q0 = unpk(mA.x), q1 = unpk(mA.y), q2 = unpk(mA.z), q3 = unpk(mA.w);
      float qa[8] = {q0.x, q0.y, q1.x, q1.y, q2.x, q2.y, q3.x, q3.y};
#pragma unroll
      for (int j = 0; j < 8; j++) {
        acc[0][j] = fmaf(wA.x, qa[j], acc[0][j]);
        acc[1][j] = fmaf(wA.y, qa[j], acc[1][j]);
        acc[2][j] = fmaf(wA.z, qa[j], acc[2][j]);
        acc[3][j] = fmaf(wA.w, qa[j], acc[3][j]);
      }
      dn0 += wA.x; dn1 += wA.y; dn2 += wA.z; dn3 += wA.w;
      q0 = unpk(mB.x); q1 = unpk(mB.y); q2 = unpk(mB.z); q3 = unpk(mB.w);
      float qb[8] = {q0.x, q0.y, q1.x, q1.y, q2.x, q2.y, q3.x, q3.y};
#pragma unroll
      for (int j = 0; j < 8; j++) {
        acc[0][j] = fmaf(wB.x, qb[j], acc[0][j]);
        acc[1][j] = fmaf(wB.y, qb[j], acc[1][j]);
        acc[2][j] = fmaf(wB.z, qb[j], acc[2][j]);
        acc[3][j] = fmaf(wB.w, qb[j], acc[3][j]);
      }
      dn0 += wB.x; dn1 += wB.y; dn2 += wB.z; dn3 += wB.w;
    }
    if (e < e1) {
      int sA = esrc[e];
      int iA = e - e0b;
      float4 wA = (iA < ECAP) ? awlds[iA] : awg[e];
      uint4 mA = x0[(size_t)sA * 16 + c8];
      float2 q0 = unpk(mA.x), q1 = unpk(mA.y), q2 = unpk(mA.z), q3 = unpk(mA.w);
      float qa[8] = {q0.x, q0.y, q1.x, q1.y, q2.x, q2.y, q3.x, q3.y};
#pragma unroll
      for (int j = 0; j < 8; j++) {
        acc[0][j] = fmaf(wA.x, qa[j], acc[0][j]);
        acc[1][j] = fmaf(wA.y, qa[j], acc[1][j]);
        acc[2][j] = fmaf(wA.z, qa[j], acc[2][j]);
        acc[3][j] = fmaf(wA.w, qa[j], acc[3][j]);
      }
      dn0 += wA.x; dn1 += wA.y; dn2 += wA.z; dn3 += wA.w;
    }
    float ivh[4] = {1.f / dn0, 1.f / dn1, 1.f / dn2, 1.f / dn3};
#pragma unroll
    for (int h = 0; h < 4; h++) {
      uint4 o;
      o.x = pk(acc[h][0] * ivh[h], acc[h][1] * ivh[h]);
      o.y = pk(acc[h][2] * ivh[h], acc[h][3] * ivh[h]);
      o.z = pk(acc[h][4] * ivh[h], acc[h][5] * ivh[h]);
      o.w = pk(acc[h][6] * ivh[h], acc[h][7] * ivh[h]);
      *(uint4*)(lds + rsub * LDW + h * 128 + c8 * 8) = o;
    }
  }
  __syncthreads();
  int wv = tid >> 6, lane = tid & 63, quad = lane >> 4, l16 = lane & 15;
  int arow = l16 * LDW;                    // all waves share the 16 rows
  // ---- phase B: x1 = ELU(y1 @ W1_head + b1); wave wv does head wv (in-place cols) ----
  {
    int h = wv;
    f4v acc[8] = {};
#pragma unroll
    for (int ks = 0; ks < 4; ks++) {
      s8v a = *(const s8v*)(lds + arow + h * 128 + ks * 32 + quad * 8);
#pragma unroll
      for (int nt = 0; nt < 8; nt++) {
        s8v bf = Bp1[(size_t)((h * 8 + nt) * 4 + ks) * 64 + lane];
        acc[nt] = __builtin_amdgcn_mfma_f32_16x16x32_bf16(a, bf, acc[nt], 0, 0, 0);
      }
    }
#pragma unroll
    for (int nt = 0; nt < 8; nt++) {
      float bb = b1[h * 128 + nt * 16 + l16];
#pragma unroll
      for (int r = 0; r < 4; r++) {
        float vv = acc[nt][r] + bb;
        vv = vv > 0.f ? vv : (__expf(vv) - 1.f);
        lds[(quad * 4 + r) * LDW + h * 128 + nt * 16 + l16] = f2bf_bits(vv);
      }
    }
  }
  __syncthreads();
  // ---- phase C: xp2 = x1 @ W2 (K=512); wave wv does output tiles {2wv, 2wv+1} ----
  f4v acc2[2] = {};
  for (int ks = 0; ks < 16; ks++) {
    s8v a = *(const s8v*)(lds + arow + ks * 32 + quad * 8);
#pragma unroll
    for (int j = 0; j < 2; j++) {
      int nt = wv * 2 + j;
      s8v bf = Bp2[(size_t)(nt * 16 + ks) * 64 + lane];
      acc2[j] = __builtin_amdgcn_mfma_f32_16x16x32_bf16(a, bf, acc2[j], 0, 0, 0);
    }
  }
  __syncthreads();   // all phase-C reads complete before restage (rows shared by waves)
#pragma unroll
  for (int j = 0; j < 2; j++) {
    int nt = wv * 2 + j;
#pragma unroll
    for (int r = 0; r < 4; r++)
      lds[(quad * 4 + r) * LDW + nt * 16 + l16] = f2bf_bits(acc2[j][r]);
  }
  __syncthreads();
  // ---- phase D: al2 scores; wave wv does rows wv*4..wv*4+3 ----
  float2 as = ((const float2*)a_src2)[lane];
  float2 ad = ((const float2*)a_dst2)[lane];
  for (int r = 0; r < 4; r++) {
    int row = wv * 4 + r;
    float2 x = unpk(*(const unsigned*)(lds + row * LDW + lane * 2));
    float ps = wred_sum(x.x * as.x + x.y * as.y);
    float pd = wred_sum(x.x * ad.x + x.y * ad.y);
    if (lane == 0) { als2[brow + row] = ps; ald2[brow + row] = pd; }
  }
  // ---- phase E: coalesced store of xp2 tile (16 rows x 16 uint4 = 256) ----
  {
    int row = tid >> 4, c16 = tid & 15;
    uint4 val = *(const uint4*)(lds + row * LDW + c16 * 8);
    *(uint4*)(xp2 + (size_t)(brow + row) * 128 + c16 * 8) = val;
  }
}

// ============== K7: FUSED conv2-scores + aggregate(+denom) + ELU + pool + h1 + head ===
// 1024 threads/block: one thread per (row, c8) -> 32 waves/CU for the gather loop.
__global__ __launch_bounds__(1024) void tail2_kernel(
    const uint4* __restrict__ xp,
    const float* __restrict__ als, const float* __restrict__ ald,
    const int* __restrict__ off, const int* __restrict__ esrc,
    const float* __restrict__ b2, const int* __restrict__ m_idx,
    const float* __restrict__ Wo1, const float* __restrict__ bo1,
    const float* __restrict__ Wo2, const float* __restrict__ bo2,
    float* __restrict__ out) {
  __shared__ float x2t[64 * 132];
  __shared__ float maskf[64];
  __shared__ float pl[128];
  __shared__ float red[1024];
  int g = blockIdx.x, tid = threadIdx.x;
  if (tid < 64) maskf[tid] = (m_idx[g * 64 + tid] >= 1) ? 1.f : 0.f;
  int c8 = tid & 15, rsub = tid >> 4;   // rsub in 0..63
  {
    int i = g * 64 + rsub;
    float adi = ald[i];
    float selfSc = als[i] + adi;
    selfSc = selfSc > 0.f ? selfSc : 0.2f * selfSc;
    float sw = __expf(selfSc);
    float dnm = sw;
    uint4 xv = xp[(size_t)i * 16 + c8];
    float2 p0 = unpk(xv.x), p1 = unpk(xv.y), p2 = unpk(xv.z), p3 = unpk(xv.w);
    float a0 = sw * p0.x, a1 = sw * p0.y, a2 = sw * p1.x, a3 = sw * p1.y;
    float a4 = sw * p2.x, a5 = sw * p2.y, a6 = sw * p3.x, a7 = sw * p3.y;
    int s0 = off[i], s1 = off[i + 1];
    int e = s0;
    for (; e + 1 < s1; e += 2) {
      int sA = esrc[e], sB = esrc[e + 1];
      float scA = als[sA] + adi, scB = als[sB] + adi;
      scA = scA > 0.f ? scA : 0.2f * scA;
      scB = scB > 0.f ? scB : 0.2f * scB;
      float wA = __expf(scA), wB = __expf(scB);
      uint4 mA = xp[(size_t)sA * 16 + c8];
      uint4 mB = xp[(size_t)sB * 16 + c8];
      float2 q0 = unpk(mA.x), q1 = unpk(mA.y), q2 = unpk(mA.z), q3 = unpk(mA.w);
      a0 = fmaf(wA, q0.x, a0); a1 = fmaf(wA, q0.y, a1);
      a2 = fmaf(wA, q1.x, a2); a3 = fmaf(wA, q1.y, a3);
      a4 = fmaf(wA, q2.x, a4); a5 = fmaf(wA, q2.y, a5);
      a6 = fmaf(wA, q3.x, a6); a7 = fmaf(wA, q3.y, a7);
      dnm += wA;
      q0 = unpk(mB.x); q1 = unpk(mB.y); q2 = unpk(mB.z); q3 = unpk(mB.w);
      a0 = fmaf(wB, q0.x, a0); a1 = fmaf(wB, q0.y, a1);
      a2 = fmaf(wB, q1.x, a2); a3 = fmaf(wB, q1.y, a3);
      a4 = fmaf(wB, q2.x, a4); a5 = fmaf(wB, q2.y, a5);
      a6 = fmaf(wB, q3.x, a6); a7 = fmaf(wB, q3.y, a7);
      dnm += wB;
    }
    if (e < s1) {
      int sA = esrc[e];
      float scA = als[sA] + adi;
      scA = scA > 0.f ? scA : 0.2f * scA;
      float wA = __expf(scA);
      uint4 mA = xp[(size_t)sA * 16 + c8];
      float2 q0 = unpk(mA.x), q1 = unpk(mA.y), q2 = unpk(mA.z), q3 = unpk(mA.w);
      a0 = fmaf(wA, q0.x, a0); a1 = fmaf(wA, q0.y, a1);
      a2 = fmaf(wA, q1.x, a2); a3 = fmaf(wA, q1.y, a3);
      a4 = fmaf(wA, q2.x, a4); a5 = fmaf(wA, q2.y, a5);
      a6 = fmaf(wA, q3.x, a6); a7 = fmaf(wA, q3.y, a7);
      dnm += wA;
    }
    float ivv = 1.f / dnm;
    float4 bb0 = ((const float4*)b2)[c8 * 2];
    float4 bb1 = ((const float4*)b2)[c8 * 2 + 1];
    a0 = a0 * ivv + bb0.x; a1 = a1 * ivv + bb0.y; a2 = a2 * ivv + bb0.z; a3 = a3 * ivv + bb0.w;
    a4 = a4 * ivv + bb1.x; a5 = a5 * ivv + bb1.y; a6 = a6 * ivv + bb1.z; a7 = a7 * ivv + bb1.w;
    a0 = a0 > 0.f ? a0 : (__expf(a0) - 1.f);
    a1 = a1 > 0.f ? a1 : (__expf(a1) - 1.f);
    a2 = a2 > 0.f ? a2 : (__expf(a2) - 1.f);
    a3 = a3 > 0.f ? a3 : (__expf(a3) - 1.f);
    a4 = a4 > 0.f ? a4 : (__expf(a4) - 1.f);
    a5 = a5 > 0.f ? a5 : (__expf(a5) - 1.f);
    a6 = a6 > 0.f ? a6 : (__expf(a6) - 1.f);
    a7 = a7 > 0.f ? a7 : (__expf(a7) - 1.f);
    float* dp = x2t + rsub * 132 + c8 * 8;
    dp[0] = a0; dp[1] = a1; dp[2] = a2; dp[3] = a3;
    dp[4] = a4; dp[5] = a5; dp[6] = a6; dp[7] = a7;
  }
  __syncthreads();
  // masked-mean pool, 8-way split over row-eighths
  int c = tid & 127, q = tid >> 7;          // q in 0..7
  float pacc = 0.f;
  for (int n = q * 8; n < q * 8 + 8; n++) pacc += maskf[n] * x2t[n * 132 + c];
  red[tid] = pacc;
  __syncthreads();
  float cnt = 0.f;
  for (int n = 0; n < 64; n++) cnt += maskf[n];
  if (q == 0) {
    float s = red[c] + red[c + 128] + red[c + 256] + red[c + 384] +
              red[c + 512] + red[c + 640] + red[c + 768] + red[c + 896];
    pl[c] = s / cnt;
  }
  __syncthreads();
  // h1 = leaky(pool @ Wo1 + bo1), 8-way split-K
  float hacc = 0.f;
  for (int k = q * 16; k < q * 16 + 16; k++)
    hacc = fmaf(pl[k], Wo1[(size_t)k * 128 + c], hacc);
  red[tid] = hacc;
  __syncthreads();
  if (q == 0) {
    float hh = red[c] + red[c + 128] + red[c + 256] + red[c + 384] +
               red[c + 512] + red[c + 640] + red[c + 768] + red[c + 896] + bo1[c];
    hh = hh > 0.f ? hh : 0.01f * hh;
    red[c] = hh * Wo2[c];
  }
  __syncthreads();
  for (int d = 64; d; d >>= 1) {
    if (tid < d) red[tid] += red[tid + d];
    __syncthreads();
  }
  if (tid == 0) out[g] = red[0] + bo2[0];
}

extern "C" void kernel_launch(void* const* d_in, const int* in_sizes, int n_in, void* d_out,
                              int out_size, void* d_ws, size_t ws_size, hipStream_t stream) {
  (void)n_in; (void)out_size; (void)ws_size;
  bool dict_order = (in_sizes[2] == NN);
  int IM, IE, IF[25];
  if (dict_order) {
    IM = 2; IE = 3;
    const int f[25] = {0, 1, 4, 5, 6, 7, 8, 9, 10, 11, 12, 13, 14, 15, 16, 17, 18,
                       19, 20, 21, 22, 23, 24, 25, 26};
    for (int k = 0; k < 25; k++) IF[k] = f[k];
  } else {
    IM = 25; IE = 26;
    for (int k = 0; k < 25; k++) IF[k] = k;
  }
  const int* m_idx = (const int*)d_in[IM];
  const int* eidx = (const int*)d_in[IE];
  float* out = (float*)d_out;
  const int* e_src = eidx;
  const int* e_dst = eidx + EE;

  const float* t = (const float*)d_in[IF[0]];
  const float* v = (const float*)d_in[IF[1]];
  const float* Wt = (const float*)d_in[IF[2]];     const float* bt = (const float*)d_in[IF[3]];
  const float* Wv = (const float*)d_in[IF[4]];     const float* bv = (const float*)d_in[IF[5]];
  const float* emb = (const float*)d_in[IF[6]];
  const float* Wnode = (const float*)d_in[IF[7]];  const float* bnode = (const float*)d_in[IF[8]];
  const float* Wstart = (const float*)d_in[IF[9]]; const float* bstart = (const float*)d_in[IF[10]];
  const float* ln_g = (const float*)d_in[IF[11]];  const float* ln_b = (const float*)d_in[IF[12]];
  const float* W1 = (const float*)d_in[IF[13]];
  const float* a_src1 = (const float*)d_in[IF[14]]; const float* a_dst1 = (const float*)d_in[IF[15]];
  const float* b1 = (const float*)d_in[IF[16]];
  const float* W2 = (const float*)d_in[IF[17]];
  const float* a_src2 = (const float*)d_in[IF[18]]; const float* a_dst2 = (const float*)d_in[IF[19]];
  const float* b2 = (const float*)d_in[IF[20]];
  const float* Wo1 = (const float*)d_in[IF[21]];   const float* bo1 = (const float*)d_in[IF[22]];
  const float* Wo2 = (const float*)d_in[IF[23]];   const float* bo2 = (const float*)d_in[IF[24]];

  // workspace layout (~24 MB)
  char* w = (char*)d_ws;
  bf16* x0b = (bf16*)w;                               // [NN,128] bf16 [0,8) MB
  bf16* xp2b = (bf16*)(w + ((size_t)8 << 20));        // [NN,128] bf16 [8,16) MB
  size_t so = (size_t)16 << 20;
  bf16* emb2_b = (bf16*)(w + so); so += 51 * 128 * 2 + 256;
  bf16* start_b = (bf16*)(w + so); so += 512 * 128 * 2;
  float* als1 = (float*)(w + so); so += NN * 4 * 4;
  float* ald1 = (float*)(w + so); so += NN * 4 * 4;
  float* als2 = (float*)(w + so); so += NN * 4;
  float* ald2 = (float*)(w + so); so += NN * 4;
  float* aw1 = (float*)(w + so); so += EE * 4 * 4;    // 4 MB (A0 overflow only)
  float* ws1 = (float*)(w + so); so += 512 * 4;
  float* wd1 = (float*)(w + so); so += 512 * 4;
  float* Wvs = (float*)(w + so); so += 768 * 128 * 4;   // folded start weights (fp32)
  float* Wts = (float*)(w + so); so += 768 * 128 * 4;
  float* bs2 = (float*)(w + so); so += 512;
  int* indeg = (int*)(w + so); so += NN * 4;
  int* csroff = (int*)(w + so); so += (NN + 1) * 4 + 252;
  int* cursor = (int*)(w + so); so += NN * 4;
  int* esrc = (int*)(w + so); so += EE * 4;
  int* edst = (int*)(w + so); so += EE * 4;
  s8v* Bp1 = (s8v*)(w + so); so += 32 * 4 * 64 * 16;
  s8v* Bp2 = (s8v*)(w + so); so += 8 * 16 * 64 * 16;

  hipMemsetAsync(indeg, 0, NN * 4, stream);
  // K1: hist + pack + fold1 + emb2 + start-weight folds
  prep_kernel<<<1577, 256, 0, stream>>>(e_dst, indeg,
      W1, Bp1, W2, Bp2, a_src1, a_dst1, ws1, wd1,
      emb, Wnode, bnode, emb2_b,
      Wv, Wt, Wstart, bv, bt, bstart, Wvs, Wts, bs2);
  // K2: CSR scan (block 0) + start rows (blocks 1..512)
  scan_start_kernel<<<513, 1024, 0, stream>>>(indeg, csroff, cursor,
      t, v, Wvs, Wts, bs2, start_b);
  // K3: CSR fill (+edst) + fused LN + conv1 scores
  fill_ln_kernel<<<9216, 256, 0, stream>>>(e_src, e_dst, cursor, esrc, edst,
      (const unsigned*)start_b, (const unsigned*)emb2_b, m_idx, ln_g, ln_b,
      ws1, wd1, (unsigned*)x0b, als1, ald1);
  // K5: fused conv1-scores(A0) + aggregate(+denom) + conv1 GEMM + ELU + conv2 GEMM + al2
  conv12f_kernel<<<NN / 16, 256, 0, stream>>>((const uint4*)x0b,
      (float4*)aw1, (const float4*)als1, (const float4*)ald1,
      csroff, esrc, edst, Bp1, b1, Bp2, a_src2, a_dst2, (short*)xp2b, als2, ald2);
  // K7: fused conv2 scores inline + aggregate(+denom) + ELU + pool + h1 + head
  tail2_kernel<<<GG, 1024, 0, stream>>>((const uint4*)xp2b, als2, ald2,
      csroff, esrc, b2, m_idx, Wo1, bo1, Wo2, bo2, out);
}

// Round 18
// 257.553 us; speedup vs baseline: 1.0206x; 1.0206x over previous
//
#include <hip/hip_runtime.h>
#include <hip/hip_bf16.h>

typedef __hip_bfloat16 bf16;
typedef __attribute__((ext_vector_type(8))) short s8v;   // 8 bf16 (4 VGPRs)
typedef __attribute__((ext_vector_type(4))) float f4v;   // 4 fp32 acc

#define NN 32768   // total nodes
#define EE 262144  // edges
#define GG 512     // graphs
#define LDW 520    // conv12 tile stride (bf16): 520*2B -> 2-way bank alias (free)
#define ECAP 1024  // LDS edge-weight capacity per conv12f block (mean ~128)

__device__ __forceinline__ float2 unpk(unsigned u) {
  float2 r;
  r.x = __uint_as_float(u << 16);
  r.y = __uint_as_float(u & 0xffff0000u);
  return r;
}
__device__ __forceinline__ unsigned pk(float x, float y) {
  union { bf16 h[2]; unsigned u; } p;
  p.h[0] = __float2bfloat16(x);
  p.h[1] = __float2bfloat16(y);
  return p.u;
}
__device__ __forceinline__ short f2bf_bits(float x) {
  bf16 h = __float2bfloat16(x);
  return *reinterpret_cast<short*>(&h);
}
__device__ __forceinline__ float wred_sum(float v) {
#pragma unroll
  for (int o = 32; o; o >>= 1) v += __shfl_xor(v, o, 64);
  return v;
}

// pack one weight matrix into MFMA B-fragment order
__device__ __forceinline__ void packB_one(const float* W, int N, int K, int id, s8v* Bp) {
  int lane = id & 63;
  int tmp = id >> 6;
  int ksteps = K >> 5;
  int ks = tmp % ksteps;
  int nt = tmp / ksteps;
  int n = nt * 16 + (lane & 15);
  int kbase = ks * 32 + (lane >> 4) * 8;
  s8v r;
#pragma unroll
  for (int j = 0; j < 8; j++) r[j] = f2bf_bits(W[(size_t)(kbase + j) * N + n]);
  Bp[id] = r;
}

// ================= K1: hist + pack(Bp1,Bp2) + fold1 + emb2 + start-weight folds ======
__global__ __launch_bounds__(256) void prep_kernel(
    const int* __restrict__ dst, int* __restrict__ indeg,
    const float* __restrict__ W1, s8v* __restrict__ Bp1,
    const float* __restrict__ W2, s8v* __restrict__ Bp2,
    const float* __restrict__ a_src1, const float* __restrict__ a_dst1,
    float* __restrict__ ws1, float* __restrict__ wd1,
    const float* __restrict__ emb, const float* __restrict__ Wnode,
    const float* __restrict__ bnode, bf16* __restrict__ emb2_b,
    const float* __restrict__ Wv, const float* __restrict__ Wt,
    const float* __restrict__ Ws,
    const float* __restrict__ bv, const float* __restrict__ bt,
    const float* __restrict__ bstart,
    float* __restrict__ Wvs, float* __restrict__ Wts,
    float* __restrict__ bs2) {
  int b = blockIdx.x, tid = threadIdx.x;
  if (b < 1024) {
    int e = b * 256 + tid;
    atomicAdd(&indeg[dst[e]], 1);
  } else if (b < 1056) {
    packB_one(W1, 512, 128, (b - 1024) * 256 + tid, Bp1);
  } else if (b < 1088) {
    packB_one(W2, 128, 512, (b - 1056) * 256 + tid, Bp2);
  } else if (b < 1090) {
    int id = (b - 1088) * 256 + tid;   // 512 outputs
    int h = id >> 7, k = id & 127;
    float s = 0.f, d = 0.f;
    for (int c = 0; c < 128; c++) {
      float w0 = W1[(size_t)k * 512 + h * 128 + c];
      s = fmaf(w0, a_src1[h * 128 + c], s);
      d = fmaf(w0, a_dst1[h * 128 + c], d);
    }
    ws1[id] = s;
    wd1[id] = d;
  } else if (b < 1192) {
    // emb2 = emb @ Wnode + bnode  (M=51,N=128,K=128), split-K over 4 slices
    __shared__ float red[256];
    int bb = b - 1090;
    int lo = tid & 63, slice = tid >> 6;
    long oid = (long)bb * 64 + lo;
    bool live = (oid < 51L * 128);
    int m = 0, n = 0;
    if (live) { m = (int)(oid >> 7); n = (int)(oid & 127); }
    float acc = 0.f;
    if (live) {
      const float* Ar = emb + (size_t)m * 128;
      for (int k = slice * 32; k < slice * 32 + 32; k++)
        acc = fmaf(Ar[k], Wnode[(size_t)k * 128 + n], acc);
    }
    red[tid] = acc;
    __syncthreads();
    if (slice == 0 && live) {
      float v = red[lo] + red[64 + lo] + red[128 + lo] + red[192 + lo];
      emb2_b[(size_t)m * 128 + n] = __float2bfloat16(v + bnode[n]);
    }
  } else if (b < 1576) {
    // folded start weights (fp32): Wvs = Wv @ Ws[0:128,:], Wts = Wt @ Ws[128:256,:]
    int id = (b - 1192) * 256 + tid;   // [0, 98304) pairs
    bool isT = id >= 49152;
    int o = isT ? id - 49152 : id;
    int k = o >> 6, cp = o & 63, c0 = cp * 2;
    const float* Wrow = (isT ? Wt : Wv) + (size_t)k * 128;
    const float* Wsc = Ws + (isT ? (size_t)128 * 128 : 0);
    float s0 = 0.f, s1 = 0.f;
    for (int j = 0; j < 128; j++) {
      float w = Wrow[j];
      float2 q = *(const float2*)(Wsc + (size_t)j * 128 + c0);
      s0 = fmaf(w, q.x, s0);
      s1 = fmaf(w, q.y, s1);
    }
    float* dp = (isT ? Wts : Wvs) + (size_t)k * 128 + c0;
    dp[0] = s0;
    dp[1] = s1;
  } else {
    // b_s = bstart + bv @ Ws[0:128,:] + bt @ Ws[128:256,:]
    if (tid < 128) {
      float s = bstart[tid];
      for (int k = 0; k < 128; k++) {
        s = fmaf(bv[k], Ws[(size_t)k * 128 + tid], s);
        s = fmaf(bt[k], Ws[(size_t)(128 + k) * 128 + tid], s);
      }
      bs2[tid] = s;
    }
  }
}

// ================= K2: block 0 = CSR scan; blocks 1..512 = start rows ================
__global__ __launch_bounds__(1024) void scan_start_kernel(
    const int* __restrict__ indeg, int* __restrict__ off, int* __restrict__ cursor,
    const float* __restrict__ tf, const float* __restrict__ vf,
    const float* __restrict__ Wvs, const float* __restrict__ Wts,
    const float* __restrict__ bs2, bf16* __restrict__ start_b) {
  int t = threadIdx.x;
  if (blockIdx.x == 0) {
    __shared__ int sh[1024];
    int loc[32];
    int s = 0;
    int base = t * 32;
#pragma unroll
    for (int j = 0; j < 32; j++) { loc[j] = indeg[base + j]; s += loc[j]; }
    sh[t] = s;
    __syncthreads();
    for (int d = 1; d < 1024; d <<= 1) {
      int v = (t >= d) ? sh[t - d] : 0;
      __syncthreads();
      sh[t] += v;
      __syncthreads();
    }
    int run = (t == 0) ? 0 : sh[t - 1];
#pragma unroll
    for (int j = 0; j < 32; j++) { off[base + j] = run; cursor[base + j] = run; run += loc[j]; }
    if (t == 1023) off[NN] = run;
    return;
  }
  __shared__ float red[1024];
  int g = blockIdx.x - 1;
  int c = t & 127, slice = t >> 7;          // 8 K-slices of 96
  const float* vrow = vf + (size_t)g * 768;
  const float* trow = tf + (size_t)g * 768;
  float acc = 0.f;
  int k0 = slice * 96;
#pragma unroll 4
  for (int k = k0; k < k0 + 96; k++)
    acc = fmaf(vrow[k], Wvs[(size_t)k * 128 + c], fmaf(trow[k], Wts[(size_t)k * 128 + c], acc));
  red[t] = acc;
  __syncthreads();
  if (t < 512) red[t] += red[t + 512];
  __syncthreads();
  if (t < 256) red[t] += red[t + 256];
  __syncthreads();
  if (t < 128) {
    float s = red[t] + red[t + 128] + bs2[t];
    start_b[(size_t)g * 128 + t] = __float2bfloat16(s);
  }
}

// ================= K3: CSR fill (blocks 0-1023, also edst) + fused LN + conv1 scores =
__global__ __launch_bounds__(256) void fill_ln_kernel(
    const int* __restrict__ src, const int* __restrict__ dst,
    int* __restrict__ cursor, int* __restrict__ esrc, int* __restrict__ edst,
    const unsigned* __restrict__ start_b, const unsigned* __restrict__ emb2_b,
    const int* __restrict__ m_idx, const float* __restrict__ lng,
    const float* __restrict__ lnb, const float* __restrict__ ws1,
    const float* __restrict__ wd1, unsigned* __restrict__ x0b,
    float* __restrict__ als, float* __restrict__ ald) {
  int b = blockIdx.x;
  if (b < 1024) {
    int e = b * 256 + threadIdx.x;
    int d = dst[e];
    int p = atomicAdd(&cursor[d], 1);
    esrc[p] = src[e];
    edst[p] = d;
    return;
  }
  int bb = b - 1024;
  int i = bb * 4 + (threadIdx.x >> 6);
  int lane = threadIdx.x & 63;
  int g = i >> 6, n = i & 63;
  const unsigned* row = (n == 0) ? (start_b + (size_t)g * 64) : (emb2_b + (size_t)m_idx[i] * 64);
  float2 v = unpk(row[lane]);
  float mu = wred_sum(v.x + v.y) * (1.f / 128.f);
  float dx = v.x - mu, dy = v.y - mu;
  float var = wred_sum(dx * dx + dy * dy) * (1.f / 128.f);
  float rstd = rsqrtf(var + 1e-6f);
  float2 gg = ((const float2*)lng)[lane];
  float2 bbv = ((const float2*)lnb)[lane];
  float xx = dx * rstd * gg.x + bbv.x;
  float xy = dy * rstd * gg.y + bbv.y;
  x0b[(size_t)i * 64 + lane] = pk(xx, xy);
#pragma unroll
  for (int h = 0; h < 4; h++) {
    float2 s2 = ((const float2*)(ws1 + h * 128))[lane];
    float2 d2 = ((const float2*)(wd1 + h * 128))[lane];
    float ps = wred_sum(xx * s2.x + xy * s2.y);
    float pd = wred_sum(xx * d2.x + xy * d2.y);
    if (lane == 0) { als[i * 4 + h] = ps; ald[i * 4 + h] = pd; }
  }
}

// ================= K5: FUSED conv1-scores(A0) + aggregate(+denom) + GEMMs + al2 =======
// Round-9 structure (256 thr, 16 rows, x2 edge unroll) + phase A0: per-edge scores
// computed ONCE into LDS (overflow -> global awg), replacing the escore1 kernel.
__global__ __launch_bounds__(256) void conv12f_kernel(
    const uint4* __restrict__ x0,
    float4* __restrict__ awg,
    const float4* __restrict__ als4, const float4* __restrict__ ald4,
    const int* __restrict__ off, const int* __restrict__ esrc,
    const int* __restrict__ edst,
    const s8v* __restrict__ Bp1, const float* __restrict__ b1,
    const s8v* __restrict__ Bp2,
    const float* __restrict__ a_src2, const float* __restrict__ a_dst2,
    short* __restrict__ xp2, float* __restrict__ als2, float* __restrict__ ald2) {
  __shared__ short lds[16 * LDW];
  __shared__ float4 awlds[ECAP];
  int tid = threadIdx.x;
  int brow = blockIdx.x * 16;
  int e0b = off[brow], e1b = off[brow + 16];
  // ---- phase A0: edge scores, one thread per edge, into LDS (overflow -> global) ----
  for (int e = e0b + tid; e < e1b; e += 256) {
    float4 a = als4[esrc[e]];
    float4 d = ald4[edst[e]];
    float v0 = a.x + d.x, v1 = a.y + d.y, v2 = a.z + d.z, v3 = a.w + d.w;
    v0 = v0 > 0.f ? v0 : 0.2f * v0; v1 = v1 > 0.f ? v1 : 0.2f * v1;
    v2 = v2 > 0.f ? v2 : 0.2f * v2; v3 = v3 > 0.f ? v3 : 0.2f * v3;
    float4 wv = make_float4(__expf(v0), __expf(v1), __expf(v2), __expf(v3));
    int idx = e - e0b;
    if (idx < ECAP) awlds[idx] = wv;
    else awg[e] = wv;
  }
  __syncthreads();
  // ---- phase A: aggregate y1 tile (4 heads x 128 cols) into LDS, denom fused ----
  {
    int c8 = tid & 15, rsub = tid >> 4;   // rsub 0..15, one row per thread-slice
    int i = brow + rsub;
    float4 sa = als4[i], sd = ald4[i];
    float u0 = sa.x + sd.x, u1 = sa.y + sd.y, u2 = sa.z + sd.z, u3 = sa.w + sd.w;
    u0 = u0 > 0.f ? u0 : 0.2f * u0; u1 = u1 > 0.f ? u1 : 0.2f * u1;
    u2 = u2 > 0.f ? u2 : 0.2f * u2; u3 = u3 > 0.f ? u3 : 0.2f * u3;
    float sw0 = __expf(u0), sw1 = __expf(u1), sw2 = __expf(u2), sw3 = __expf(u3);
    float dn0 = sw0, dn1 = sw1, dn2 = sw2, dn3 = sw3;
    uint4 xv = x0[(size_t)i * 16 + c8];
    float x[8];
    { float2 p0 = unpk(xv.x), p1 = unpk(xv.y), p2 = unpk(xv.z), p3 = unpk(xv.w);
      x[0]=p0.x; x[1]=p0.y; x[2]=p1.x; x[3]=p1.y; x[4]=p2.x; x[5]=p2.y; x[6]=p3.x; x[7]=p3.y; }
    float acc[4][8];
#pragma unroll
    for (int j = 0; j < 8; j++) {
      acc[0][j] = sw0 * x[j]; acc[1][j] = sw1 * x[j];
      acc[2][j] = sw2 * x[j]; acc[3][j] = sw3 * x[j];
    }
    int e0 = off[i], e1 = off[i + 1];
    int e = e0;
    for (; e + 1 < e1; e += 2) {
      int sA = esrc[e], sB = esrc[e + 1];
      int iA = e - e0b, iB = iA + 1;
      float4 wA = (iA < ECAP) ? awlds[iA] : awg[e];
      float4 wB = (iB < ECAP) ? awlds[iB] : awg[e + 1];
      uint4 mA = x0[(size_t)sA * 16 + c8];
      uint4 mB = x0[(size_t)sB * 16 + c8];
      float2 q0 = unpk(mA.x), q1 = unpk(mA.y), q2 = unpk(mA.z), q3 = unpk(mA.w);
      float qa[8] = {q0.x, q0.y, q1.x, q1.y, q2.x, q2.y, q3.x, q3.y};
#pragma unroll
      for (int j = 0; j < 8; j++) {
        acc[0][j] = fmaf(wA.x, qa[j], acc[0][j]);
        acc[1][j] = fmaf(wA.y, qa[j], acc[1][j]);
        acc[2][j] = fmaf(wA.z, qa[j], acc[2][j]);
        acc[3][j] = fmaf(wA.w, qa[j], acc[3][j]);
      }
      dn0 += wA.x; dn1 += wA.y; dn2 += wA.z; dn3 += wA.w;
      q0 = unpk(mB.x); q1 = unpk(mB.y); q2 = unpk(mB.z); q3 = unpk(mB.w);
      float qb[8] = {q0.x, q0.y, q1.x, q1.y, q2.x, q2.y, q3.x, q3.y};
#pragma unroll
      for (int j = 0; j < 8; j++) {
        acc[0][j] = fmaf(wB.x, qb[j], acc[0][j]);
        acc[1][j] = fmaf(wB.y, qb[j], acc[1][j]);
        acc[2][j] = fmaf(wB.z, qb[j], acc[2][j]);
        acc[3][j] = fmaf(wB.w, qb[j], acc[3][j]);
      }
      dn0 += wB.x; dn1 += wB.y; dn2 += wB.z; dn3 += wB.w;
    }
    if (e < e1) {
      int sA = esrc[e];
      int iA = e - e0b;
      float4 wA = (iA < ECAP) ? awlds[iA] : awg[e];
      uint4 mA = x0[(size_t)sA * 16 + c8];
      float2 q0 = unpk(mA.x), q1 = unpk(mA.y), q2 = unpk(mA.z), q3 = unpk(mA.w);
      float qa[8] = {q0.x, q0.y, q1.x, q1.y, q2.x, q2.y, q3.x, q3.y};
#pragma unroll
      for (int j = 0; j < 8; j++) {
        acc[0][j] = fmaf(wA.x, qa[j], acc[0][j]);
        acc[1][j] = fmaf(wA.y, qa[j], acc[1][j]);
        acc[2][j] = fmaf(wA.z, qa[j], acc[2][j]);
        acc[3][j] = fmaf(wA.w, qa[j], acc[3][j]);
      }
      dn0 += wA.x; dn1 += wA.y; dn2 += wA.z; dn3 += wA.w;
    }
    float ivh[4] = {1.f / dn0, 1.f / dn1, 1.f / dn2, 1.f / dn3};
#pragma unroll
    for (int h = 0; h < 4; h++) {
      uint4 o;
      o.x = pk(acc[h][0] * ivh[h], acc[h][1] * ivh[h]);
      o.y = pk(acc[h][2] * ivh[h], acc[h][3] * ivh[h]);
      o.z = pk(acc[h][4] * ivh[h], acc[h][5] * ivh[h]);
      o.w = pk(acc[h][6] * ivh[h], acc[h][7] * ivh[h]);
      *(uint4*)(lds + rsub * LDW + h * 128 + c8 * 8) = o;
    }
  }
  __syncthreads();
  int wv = tid >> 6, lane = tid & 63, quad = lane >> 4, l16 = lane & 15;
  int arow = l16 * LDW;                    // all waves share the 16 rows
  // ---- phase B: x1 = ELU(y1 @ W1_head + b1); wave wv does head wv (in-place cols) ----
  {
    int h = wv;
    f4v acc[8] = {};
#pragma unroll
    for (int ks = 0; ks < 4; ks++) {
      s8v a = *(const s8v*)(lds + arow + h * 128 + ks * 32 + quad * 8);
#pragma unroll
      for (int nt = 0; nt < 8; nt++) {
        s8v bf = Bp1[(size_t)((h * 8 + nt) * 4 + ks) * 64 + lane];
        acc[nt] = __builtin_amdgcn_mfma_f32_16x16x32_bf16(a, bf, acc[nt], 0, 0, 0);
      }
    }
#pragma unroll
    for (int nt = 0; nt < 8; nt++) {
      float bb = b1[h * 128 + nt * 16 + l16];
#pragma unroll
      for (int r = 0; r < 4; r++) {
        float vv = acc[nt][r] + bb;
        vv = vv > 0.f ? vv : (__expf(vv) - 1.f);
        lds[(quad * 4 + r) * LDW + h * 128 + nt * 16 + l16] = f2bf_bits(vv);
      }
    }
  }
  __syncthreads();
  // ---- phase C: xp2 = x1 @ W2 (K=512); wave wv does output tiles {2wv, 2wv+1} ----
  f4v acc2[2] = {};
  for (int ks = 0; ks < 16; ks++) {
    s8v a = *(const s8v*)(lds + arow + ks * 32 + quad * 8);
#pragma unroll
    for (int j = 0; j < 2; j++) {
      int nt = wv * 2 + j;
      s8v bf = Bp2[(size_t)(nt * 16 + ks) * 64 + lane];
      acc2[j] = __builtin_amdgcn_mfma_f32_16x16x32_bf16(a, bf, acc2[j], 0, 0, 0);
    }
  }
  __syncthreads();   // all phase-C reads complete before restage (rows shared by waves)
#pragma unroll
  for (int j = 0; j < 2; j++) {
    int nt = wv * 2 + j;
#pragma unroll
    for (int r = 0; r < 4; r++)
      lds[(quad * 4 + r) * LDW + nt * 16 + l16] = f2bf_bits(acc2[j][r]);
  }
  __syncthreads();
  // ---- phase D: al2 scores; wave wv does rows wv*4..wv*4+3 ----
  float2 as = ((const float2*)a_src2)[lane];
  float2 ad = ((const float2*)a_dst2)[lane];
  for (int r = 0; r < 4; r++) {
    int row = wv * 4 + r;
    float2 x = unpk(*(const unsigned*)(lds + row * LDW + lane * 2));
    float ps = wred_sum(x.x * as.x + x.y * as.y);
    float pd = wred_sum(x.x * ad.x + x.y * ad.y);
    if (lane == 0) { als2[brow + row] = ps; ald2[brow + row] = pd; }
  }
  // ---- phase E: coalesced store of xp2 tile (16 rows x 16 uint4 = 256) ----
  {
    int row = tid >> 4, c16 = tid & 15;
    uint4 val = *(const uint4*)(lds + row * LDW + c16 * 8);
    *(uint4*)(xp2 + (size_t)(brow + row) * 128 + c16 * 8) = val;
  }
}

// ============== K7: FUSED conv2-scores + aggregate(+denom) + ELU + pool + h1 + head ===
// 1024 threads/block: one thread per (row, c8) -> 32 waves/CU for the gather loop.
__global__ __launch_bounds__(1024) void tail2_kernel(
    const uint4* __restrict__ xp,
    const float* __restrict__ als, const float* __restrict__ ald,
    const int* __restrict__ off, const int* __restrict__ esrc,
    const float* __restrict__ b2, const int* __restrict__ m_idx,
    const float* __restrict__ Wo1, const float* __restrict__ bo1,
    const float* __restrict__ Wo2, const float* __restrict__ bo2,
    float* __restrict__ out) {
  __shared__ float x2t[64 * 132];
  __shared__ float maskf[64];
  __shared__ float pl[128];
  __shared__ float red[1024];
  int g = blockIdx.x, tid = threadIdx.x;
  if (tid < 64) maskf[tid] = (m_idx[g * 64 + tid] >= 1) ? 1.f : 0.f;
  int c8 = tid & 15, rsub = tid >> 4;   // rsub in 0..63
  {
    int i = g * 64 + rsub;
    float adi = ald[i];
    float selfSc = als[i] + adi;
    selfSc = selfSc > 0.f ? selfSc : 0.2f * selfSc;
    float sw = __expf(selfSc);
    float dnm = sw;
    uint4 xv = xp[(size_t)i * 16 + c8];
    float2 p0 = unpk(xv.x), p1 = unpk(xv.y), p2 = unpk(xv.z), p3 = unpk(xv.w);
    float a0 = sw * p0.x, a1 = sw * p0.y, a2 = sw * p1.x, a3 = sw * p1.y;
    float a4 = sw * p2.x, a5 = sw * p2.y, a6 = sw * p3.x, a7 = sw * p3.y;
    int s0 = off[i], s1 = off[i + 1];
    int e = s0;
    for (; e + 1 < s1; e += 2) {
      int sA = esrc[e], sB = esrc[e + 1];
      float scA = als[sA] + adi, scB = als[sB] + adi;
      scA = scA > 0.f ? scA : 0.2f * scA;
      scB = scB > 0.f ? scB : 0.2f * scB;
      float wA = __expf(scA), wB = __expf(scB);
      uint4 mA = xp[(size_t)sA * 16 + c8];
      uint4 mB = xp[(size_t)sB * 16 + c8];
      float2 q0 = unpk(mA.x), q1 = unpk(mA.y), q2 = unpk(mA.z), q3 = unpk(mA.w);
      a0 = fmaf(wA, q0.x, a0); a1 = fmaf(wA, q0.y, a1);
      a2 = fmaf(wA, q1.x, a2); a3 = fmaf(wA, q1.y, a3);
      a4 = fmaf(wA, q2.x, a4); a5 = fmaf(wA, q2.y, a5);
      a6 = fmaf(wA, q3.x, a6); a7 = fmaf(wA, q3.y, a7);
      dnm += wA;
      q0 = unpk(mB.x); q1 = unpk(mB.y); q2 = unpk(mB.z); q3 = unpk(mB.w);
      a0 = fmaf(wB, q0.x, a0); a1 = fmaf(wB, q0.y, a1);
      a2 = fmaf(wB, q1.x, a2); a3 = fmaf(wB, q1.y, a3);
      a4 = fmaf(wB, q2.x, a4); a5 = fmaf(wB, q2.y, a5);
      a6 = fmaf(wB, q3.x, a6); a7 = fmaf(wB, q3.y, a7);
      dnm += wB;
    }
    if (e < s1) {
      int sA = esrc[e];
      float scA = als[sA] + adi;
      scA = scA > 0.f ? scA : 0.2f * scA;
      float wA = __expf(scA);
      uint4 mA = xp[(size_t)sA * 16 + c8];
      float2 q0 = unpk(mA.x), q1 = unpk(mA.y), q2 = unpk(mA.z), q3 = unpk(mA.w);
      a0 = fmaf(wA, q0.x, a0); a1 = fmaf(wA, q0.y, a1);
      a2 = fmaf(wA, q1.x, a2); a3 = fmaf(wA, q1.y, a3);
      a4 = fmaf(wA, q2.x, a4); a5 = fmaf(wA, q2.y, a5);
      a6 = fmaf(wA, q3.x, a6); a7 = fmaf(wA, q3.y, a7);
      dnm += wA;
    }
    float ivv = 1.f / dnm;
    float4 bb0 = ((const float4*)b2)[c8 * 2];
    float4 bb1 = ((const float4*)b2)[c8 * 2 + 1];
    a0 = a0 * ivv + bb0.x; a1 = a1 * ivv + bb0.y; a2 = a2 * ivv + bb0.z; a3 = a3 * ivv + bb0.w;
    a4 = a4 * ivv + bb1.x; a5 = a5 * ivv + bb1.y; a6 = a6 * ivv + bb1.z; a7 = a7 * ivv + bb1.w;
    a0 = a0 > 0.f ? a0 : (__expf(a0) - 1.f);
    a1 = a1 > 0.f ? a1 : (__expf(a1) - 1.f);
    a2 = a2 > 0.f ? a2 : (__expf(a2) - 1.f);
    a3 = a3 > 0.f ? a3 : (__expf(a3) - 1.f);
    a4 = a4 > 0.f ? a4 : (__expf(a4) - 1.f);
    a5 = a5 > 0.f ? a5 : (__expf(a5) - 1.f);
    a6 = a6 > 0.f ? a6 : (__expf(a6) - 1.f);
    a7 = a7 > 0.f ? a7 : (__expf(a7) - 1.f);
    float* dp = x2t + rsub * 132 + c8 * 8;
    dp[0] = a0; dp[1] = a1; dp[2] = a2; dp[3] = a3;
    dp[4] = a4; dp[5] = a5; dp[6] = a6; dp[7] = a7;
  }
  __syncthreads();
  // masked-mean pool, 8-way split over row-eighths
  int c = tid & 127, q = tid >> 7;          // q in 0..7
  float pacc = 0.f;
  for (int n = q * 8; n < q * 8 + 8; n++) pacc += maskf[n] * x2t[n * 132 + c];
  red[tid] = pacc;
  __syncthreads();
  float cnt = 0.f;
  for (int n = 0; n < 64; n++) cnt += maskf[n];
  if (q == 0) {
    float s = red[c] + red[c + 128] + red[c + 256] + red[c + 384] +
              red[c + 512] + red[c + 640] + red[c + 768] + red[c + 896];
    pl[c] = s / cnt;
  }
  __syncthreads();
  // h1 = leaky(pool @ Wo1 + bo1), 8-way split-K
  float hacc = 0.f;
  for (int k = q * 16; k < q * 16 + 16; k++)
    hacc = fmaf(pl[k], Wo1[(size_t)k * 128 + c], hacc);
  red[tid] = hacc;
  __syncthreads();
  if (q == 0) {
    float hh = red[c] + red[c + 128] + red[c + 256] + red[c + 384] +
               red[c + 512] + red[c + 640] + red[c + 768] + red[c + 896] + bo1[c];
    hh = hh > 0.f ? hh : 0.01f * hh;
    red[c] = hh * Wo2[c];
  }
  __syncthreads();
  for (int d = 64; d; d >>= 1) {
    if (tid < d) red[tid] += red[tid + d];
    __syncthreads();
  }
  if (tid == 0) out[g] = red[0] + bo2[0];
}

extern "C" void kernel_launch(void* const* d_in, const int* in_sizes, int n_in, void* d_out,
                              int out_size, void* d_ws, size_t ws_size, hipStream_t stream) {
  (void)n_in; (void)out_size; (void)ws_size;
  bool dict_order = (in_sizes[2] == NN);
  int IM, IE, IF[25];
  if (dict_order) {
    IM = 2; IE = 3;
    const int f[25] = {0, 1, 4, 5, 6, 7, 8, 9, 10, 11, 12, 13, 14, 15, 16, 17, 18,
                       19, 20, 21, 22, 23, 24, 25, 26};
    for (int k = 0; k < 25; k++) IF[k] = f[k];
  } else {
    IM = 25; IE = 26;
    for (int k = 0; k < 25; k++) IF[k] = k;
  }
  const int* m_idx = (const int*)d_in[IM];
  const int* eidx = (const int*)d_in[IE];
  float* out = (float*)d_out;
  const int* e_src = eidx;
  const int* e_dst = eidx + EE;

  const float* t = (const float*)d_in[IF[0]];
  const float* v = (const float*)d_in[IF[1]];
  const float* Wt = (const float*)d_in[IF[2]];     const float* bt = (const float*)d_in[IF[3]];
  const float* Wv = (const float*)d_in[IF[4]];     const float* bv = (const float*)d_in[IF[5]];
  const float* emb = (const float*)d_in[IF[6]];
  const float* Wnode = (const float*)d_in[IF[7]];  const float* bnode = (const float*)d_in[IF[8]];
  const float* Wstart = (const float*)d_in[IF[9]]; const float* bstart = (const float*)d_in[IF[10]];
  const float* ln_g = (const float*)d_in[IF[11]];  const float* ln_b = (const float*)d_in[IF[12]];
  const float* W1 = (const float*)d_in[IF[13]];
  const float* a_src1 = (const float*)d_in[IF[14]]; const float* a_dst1 = (const float*)d_in[IF[15]];
  const float* b1 = (const float*)d_in[IF[16]];
  const float* W2 = (const float*)d_in[IF[17]];
  const float* a_src2 = (const float*)d_in[IF[18]]; const float* a_dst2 = (const float*)d_in[IF[19]];
  const float* b2 = (const float*)d_in[IF[20]];
  const float* Wo1 = (const float*)d_in[IF[21]];   const float* bo1 = (const float*)d_in[IF[22]];
  const float* Wo2 = (const float*)d_in[IF[23]];   const float* bo2 = (const float*)d_in[IF[24]];

  // workspace layout (~24 MB)
  char* w = (char*)d_ws;
  bf16* x0b = (bf16*)w;                               // [NN,128] bf16 [0,8) MB
  bf16* xp2b = (bf16*)(w + ((size_t)8 << 20));        // [NN,128] bf16 [8,16) MB
  size_t so = (size_t)16 << 20;
  bf16* emb2_b = (bf16*)(w + so); so += 51 * 128 * 2 + 256;
  bf16* start_b = (bf16*)(w + so); so += 512 * 128 * 2;
  float* als1 = (float*)(w + so); so += NN * 4 * 4;
  float* ald1 = (float*)(w + so); so += NN * 4 * 4;
  float* als2 = (float*)(w + so); so += NN * 4;
  float* ald2 = (float*)(w + so); so += NN * 4;
  float* aw1 = (float*)(w + so); so += EE * 4 * 4;    // 4 MB (A0 overflow only)
  float* ws1 = (float*)(w + so); so += 512 * 4;
  float* wd1 = (float*)(w + so); so += 512 * 4;
  float* Wvs = (float*)(w + so); so += 768 * 128 * 4;   // folded start weights (fp32)
  float* Wts = (float*)(w + so); so += 768 * 128 * 4;
  float* bs2 = (float*)(w + so); so += 512;
  int* indeg = (int*)(w + so); so += NN * 4;
  int* csroff = (int*)(w + so); so += (NN + 1) * 4 + 252;
  int* cursor = (int*)(w + so); so += NN * 4;
  int* esrc = (int*)(w + so); so += EE * 4;
  int* edst = (int*)(w + so); so += EE * 4;
  s8v* Bp1 = (s8v*)(w + so); so += 32 * 4 * 64 * 16;
  s8v* Bp2 = (s8v*)(w + so); so += 8 * 16 * 64 * 16;

  hipMemsetAsync(indeg, 0, NN * 4, stream);
  // K1: hist + pack + fold1 + emb2 + start-weight folds
  prep_kernel<<<1577, 256, 0, stream>>>(e_dst, indeg,
      W1, Bp1, W2, Bp2, a_src1, a_dst1, ws1, wd1,
      emb, Wnode, bnode, emb2_b,
      Wv, Wt, Wstart, bv, bt, bstart, Wvs, Wts, bs2);
  // K2: CSR scan (block 0) + start rows (blocks 1..512)
  scan_start_kernel<<<513, 1024, 0, stream>>>(indeg, csroff, cursor,
      t, v, Wvs, Wts, bs2, start_b);
  // K3: CSR fill (+edst) + fused LN + conv1 scores
  fill_ln_kernel<<<9216, 256, 0, stream>>>(e_src, e_dst, cursor, esrc, edst,
      (const unsigned*)start_b, (const unsigned*)emb2_b, m_idx, ln_g, ln_b,
      ws1, wd1, (unsigned*)x0b, als1, ald1);
  // K5: fused conv1-scores(A0) + aggregate(+denom) + conv1 GEMM + ELU + conv2 GEMM + al2
  conv12f_kernel<<<NN / 16, 256, 0, stream>>>((const uint4*)x0b,
      (float4*)aw1, (const float4*)als1, (const float4*)ald1,
      csroff, esrc, edst, Bp1, b1, Bp2, a_src2, a_dst2, (short*)xp2b, als2, ald2);
  // K7: fused conv2 scores inline + aggregate(+denom) + ELU + pool + h1 + head
  tail2_kernel<<<GG, 1024, 0, stream>>>((const uint4*)xp2b, als2, ald2,
      csroff, esrc, b2, m_idx, Wo1, bo1, Wo2, bo2, out);
}